// Round 15
// baseline (1310.859 us; speedup 1.0000x reference)
//
#include <hip/hip_runtime.h>
#include <hip/hip_bf16.h>

// ---------------------------------------------------------------------------
// KimiDeltaAttention — round 15.
//  * scan v12b: identical to R14 except crosssum32 now uses the
//    __builtin_amdgcn_permlane32_swap builtin (both results modeled —
//    fixes the inline-asm register-aliasing bug that broke R14).
//  * 2048 blocks (64 vg x 32 bh) -> 2 waves/SIMD; s[4]/lane; rsum16 DPP +
//    permlane32 cross-add; triple-buffer static indices; depth-2-step FIFO.
// ---------------------------------------------------------------------------

using short8 = __attribute__((ext_vector_type(8))) short;
using f32x4  = __attribute__((ext_vector_type(4))) float;
using uint2v = __attribute__((ext_vector_type(2))) unsigned int;

static __device__ __forceinline__ ushort f2bf(float f) {
    __hip_bfloat16 h = __float2bfloat16(f);
    return *reinterpret_cast<ushort*>(&h);
}

// DPP butterfly/rotation adds (VALU-speed, no LDS pipe)
static __device__ __forceinline__ float qadd1(float x) {   // lane ^= 1 (quad)
    int y = __builtin_amdgcn_mov_dpp(__float_as_int(x), 0xB1, 0xF, 0xF, true);
    return x + __int_as_float(y);
}
static __device__ __forceinline__ float qadd2(float x) {   // lane ^= 2 (quad)
    int y = __builtin_amdgcn_mov_dpp(__float_as_int(x), 0x4E, 0xF, 0xF, true);
    return x + __int_as_float(y);
}
static __device__ __forceinline__ float radd4(float x) {   // row_ror:4
    int y = __builtin_amdgcn_mov_dpp(__float_as_int(x), 0x124, 0xF, 0xF, true);
    return x + __int_as_float(y);
}
static __device__ __forceinline__ float radd8(float x) {   // row_ror:8
    int y = __builtin_amdgcn_mov_dpp(__float_as_int(x), 0x128, 0xF, 0xF, true);
    return x + __int_as_float(y);
}
// sum within each 16-lane row (all lanes of the row get the row total)
static __device__ __forceinline__ float rsum16(float x) {
    x = qadd1(x);
    x = qadd2(x);
    x = radd4(x);
    x = radd8(x);
    return x;
}
// add lane i <-> lane i^32 via permlane32_swap builtin (both results modeled):
// new_vdst = [r0,r1,s0,s1], new_vsrc = [r2,r3,s2,s3] (16-lane rows); with
// vdst=vsrc=x the component sum gives x[i] + x[i^32] in every lane.
static __device__ __forceinline__ float crosssum32(float x) {
    const unsigned xi = (unsigned)__float_as_int(x);
    uint2v r = __builtin_amdgcn_permlane32_swap(xi, xi, false, false);
    return __int_as_float((int)r.x) + __int_as_float((int)r.y);
}

template<int W, int R> struct BufIdx { static constexpr int w = W, r = R; };

// ----------------------- row-major f32 -> bf16 cast -------------------------
__global__ __launch_bounds__(256) void cast_bf16(const float* __restrict__ in,
                                                 ushort* __restrict__ out, int n8)
{
    const int i = blockIdx.x * 256 + threadIdx.x;
    if (i >= n8) return;
    const float4 a = ((const float4*)in)[2 * i];
    const float4 b = ((const float4*)in)[2 * i + 1];
    ushort u[8] = {f2bf(a.x), f2bf(a.y), f2bf(a.z), f2bf(a.w),
                   f2bf(b.x), f2bf(b.y), f2bf(b.z), f2bf(b.w)};
    ((uint4*)out)[i] = *(uint4*)u;
}

// ------------------- transpose-cast: f32 [R,C] -> bf16 [C,R] ----------------
__global__ __launch_bounds__(256) void tcast(const float* __restrict__ in,
                                             ushort* __restrict__ out,
                                             int R, int C)
{
    __shared__ float tile[64][68];
    const int t  = threadIdx.x;
    const int c0 = blockIdx.x * 64, r0 = blockIdx.y * 64;
    const int lr = t >> 2, lc = (t & 3) * 16;
#pragma unroll
    for (int j = 0; j < 4; ++j) {
        const float4 v = *(const float4*)&in[(size_t)(r0 + lr) * C + c0 + lc + 4 * j];
        *(float4*)&tile[lr][lc + 4 * j] = v;
    }
    __syncthreads();
    const int oc = t >> 2, och = (t & 3) * 16;
    uint u[8];
#pragma unroll
    for (int j = 0; j < 8; ++j) {
        const float f0 = tile[och + 2 * j][oc];
        const float f1 = tile[och + 2 * j + 1][oc];
        u[j] = (uint)f2bf(f0) | ((uint)f2bf(f1) << 16);
    }
    uint4* dst = (uint4*)&out[(size_t)(c0 + oc) * R + r0 + och];
    dst[0] = make_uint4(u[0], u[1], u[2], u[3]);
    dst[1] = make_uint4(u[4], u[5], u[6], u[7]);
}

// --------------- bf16 MFMA GEMM: C[M,N] = A[M,K] @ Bt[N,K]^T ----------------
template<bool OUT16>
__global__ __launch_bounds__(256) void gemm_bf16(
    const ushort* __restrict__ A0, const ushort* __restrict__ A1,
    const ushort* __restrict__ A2, const ushort* __restrict__ A3,
    const ushort* __restrict__ B0, const ushort* __restrict__ B1,
    const ushort* __restrict__ B2, const ushort* __restrict__ B3,
    void* __restrict__ C0, void* __restrict__ C1,
    void* __restrict__ C2, void* __restrict__ C3,
    int M, int N, int K)
{
    const int z = blockIdx.z;
    const ushort* A = (z == 0) ? A0 : (z == 1) ? A1 : (z == 2) ? A2 : A3;
    const ushort* B = (z == 0) ? B0 : (z == 1) ? B1 : (z == 2) ? B2 : B3;
    void* Cv       = (z == 0) ? C0 : (z == 1) ? C1 : (z == 2) ? C2 : C3;

    __shared__ ushort As[128 * 64];
    __shared__ ushort Bs[128 * 64];

    const int tid  = threadIdx.x;
    const int lane = tid & 63;
    const int wave = tid >> 6;
    const int wm = wave >> 1, wn = wave & 1;
    const int bm = blockIdx.x * 128, bn = blockIdx.y * 128;

    const int srow  = tid >> 1;
    const int spart = tid & 1;

    const int ml = lane & 15;
    const int g  = lane >> 4;

    f32x4 acc[4][4];
#pragma unroll
    for (int i = 0; i < 4; ++i)
#pragma unroll
        for (int j = 0; j < 4; ++j) acc[i][j] = (f32x4){0.f, 0.f, 0.f, 0.f};

    const size_t arow_off = (size_t)(bm + srow) * K;
    const size_t brow_off = (size_t)(bn + srow) * K;

    for (int k0 = 0; k0 < K; k0 += 64) {
#pragma unroll
        for (int j = 0; j < 4; ++j) {
            const int ch = spart * 4 + j;
            const int sw = ((srow * 128 + ch * 16) ^ ((srow & 7) << 4)) >> 1;
            *(uint4*)&As[sw] = *(const uint4*)&A[arow_off + k0 + ch * 8];
            *(uint4*)&Bs[sw] = *(const uint4*)&B[brow_off + k0 + ch * 8];
        }
        __syncthreads();
#pragma unroll
        for (int kk = 0; kk < 2; ++kk) {
            short8 af[4], bfr[4];
#pragma unroll
            for (int mi = 0; mi < 4; ++mi) {
                const int row = wm * 64 + mi * 16 + ml;
                const int sw  = ((row * 128 + (kk * 4 + g) * 16) ^ ((ml & 7) << 4)) >> 1;
                af[mi] = *(const short8*)&As[sw];
            }
#pragma unroll
            for (int ni = 0; ni < 4; ++ni) {
                const int row = wn * 64 + ni * 16 + ml;
                const int sw  = ((row * 128 + (kk * 4 + g) * 16) ^ ((ml & 7) << 4)) >> 1;
                bfr[ni] = *(const short8*)&Bs[sw];
            }
#pragma unroll
            for (int mi = 0; mi < 4; ++mi)
#pragma unroll
                for (int ni = 0; ni < 4; ++ni)
                    acc[mi][ni] = __builtin_amdgcn_mfma_f32_16x16x32_bf16(
                        af[mi], bfr[ni], acc[mi][ni], 0, 0, 0);
        }
        __syncthreads();
    }

#pragma unroll
    for (int mi = 0; mi < 4; ++mi)
#pragma unroll
        for (int ni = 0; ni < 4; ++ni) {
            const int col = bn + wn * 64 + ni * 16 + ml;
#pragma unroll
            for (int r = 0; r < 4; ++r) {
                const int row = bm + wm * 64 + mi * 16 + g * 4 + r;
                if constexpr (OUT16) {
                    ((ushort*)Cv)[(size_t)row * N + col] = f2bf(acc[mi][ni][r]);
                } else {
                    ((float*)Cv)[(size_t)row * N + col] = acc[mi][ni][r];
                }
            }
        }
}

// ------------------- small-N GEMM for beta: N = 16 -------------------------
__global__ __launch_bounds__(256) void gemm_n16(
    const float* __restrict__ A, const float* __restrict__ B,
    float* __restrict__ C, int M, int Kd)
{
    const int tid  = threadIdx.x;
    const int n    = tid & 15;
    const int mloc = tid >> 4;
    const int m    = blockIdx.x * 16 + mloc;
    const float* a  = A + (size_t)m * Kd;
    const float* bn = B + n;
    float acc = 0.f;
#pragma unroll 4
    for (int k0 = 0; k0 < Kd; k0 += 8) {
        float4 a0 = *(const float4*)(a + k0);
        float4 a1 = *(const float4*)(a + k0 + 4);
        acc = fmaf(a0.x, bn[(size_t)(k0 + 0) * 16], acc);
        acc = fmaf(a0.y, bn[(size_t)(k0 + 1) * 16], acc);
        acc = fmaf(a0.z, bn[(size_t)(k0 + 2) * 16], acc);
        acc = fmaf(a0.w, bn[(size_t)(k0 + 3) * 16], acc);
        acc = fmaf(a1.x, bn[(size_t)(k0 + 4) * 16], acc);
        acc = fmaf(a1.y, bn[(size_t)(k0 + 5) * 16], acc);
        acc = fmaf(a1.z, bn[(size_t)(k0 + 6) * 16], acc);
        acc = fmaf(a1.w, bn[(size_t)(k0 + 7) * 16], acc);
    }
    C[(size_t)m * 16 + n] = acc;
}

// ---- halo save: pre-conv values at segment boundaries (race-free split) ----
__global__ __launch_bounds__(256) void halo_save(
    const float* __restrict__ q, const float* __restrict__ k,
    const float* __restrict__ v, float* __restrict__ hal)
{
    constexpr int T = 2048, C = 2048, SEG = 512;
    const int idx = blockIdx.x * 256 + threadIdx.x;   // < 9*12288
    const int cid = idx % 12288;
    const int sh  = idx / 12288;      // 0..8
    const int sg  = sh / 3 + 1;       // segment 1..3
    const int ho  = sh % 3;           // halo offset 0..2
    const int which = cid >> 12, rem = cid & 4095, b = rem >> 11, c = rem & 2047;
    const float* x = (which == 0) ? q : (which == 1) ? k : v;
    hal[idx] = x[(size_t)b * T * C + (size_t)(sg * SEG - 3 + ho) * C + c];
}

// ------- depthwise causal conv (K=4) + SiLU, in-place, 4 T-segments ---------
__global__ __launch_bounds__(256) void conv_silu(
    float* __restrict__ q, float* __restrict__ k, float* __restrict__ v,
    const float* __restrict__ wq, const float* __restrict__ wk,
    const float* __restrict__ wv, const float* __restrict__ hal)
{
    constexpr int T = 2048, C = 2048, SEG = 512;
    const int seg    = blockIdx.x & 3;
    const int colblk = blockIdx.x >> 2;
    const int cid    = colblk * 256 + threadIdx.x;
    const int which  = cid >> 12;
    const int rem    = cid & 4095;
    const int b      = rem >> 11;
    const int c      = rem & 2047;
    float* x        = (which == 0) ? q : (which == 1) ? k : v;
    const float* w  = (which == 0) ? wq : (which == 1) ? wk : wv;

    const float w0 = w[c * 4 + 0], w1 = w[c * 4 + 1];
    const float w2 = w[c * 4 + 2], w3 = w[c * 4 + 3];
    float* p = x + (size_t)b * T * C + c;
    float xm3, xm2, xm1;
    if (seg == 0) { xm3 = xm2 = xm1 = 0.f; }
    else {
        xm3 = hal[((seg - 1) * 3 + 0) * 12288 + cid];
        xm2 = hal[((seg - 1) * 3 + 1) * 12288 + cid];
        xm1 = hal[((seg - 1) * 3 + 2) * 12288 + cid];
    }

    const int t0s = seg * SEG;
    for (int t0 = t0s; t0 < t0s + SEG; t0 += 16) {
        float xt[16], yo[16];
#pragma unroll
        for (int j = 0; j < 16; ++j) xt[j] = p[(size_t)(t0 + j) * C];
#pragma unroll
        for (int j = 0; j < 16; ++j) {
            float y = fmaf(xm3, w0, fmaf(xm2, w1, fmaf(xm1, w2, xt[j] * w3)));
            yo[j] = y / (1.f + __expf(-y));
            xm3 = xm2; xm2 = xm1; xm1 = xt[j];
        }
#pragma unroll
        for (int j = 0; j < 16; ++j) p[(size_t)(t0 + j) * C] = yo[j];
    }
}

// ------ prep: l2norm(q)*D^-0.5, l2norm(k), g -> exp(-exp(A_log)*softplus) ---
__global__ __launch_bounds__(256) void prep_qkg(
    float* __restrict__ Qb, float* __restrict__ Kb, float* __restrict__ Gb,
    const float* __restrict__ A_log, const float* __restrict__ dt_bias,
    int rows)
{
    const int wave = threadIdx.x >> 6;
    const int lane = threadIdx.x & 63;
    const int row  = blockIdx.x * 4 + wave;
    if (row >= rows) return;
    const int hh = row & 15;
    const size_t base = (size_t)row * 128;

    float q0 = Qb[base + lane], q1 = Qb[base + 64 + lane];
    float k0 = Kb[base + lane], k1 = Kb[base + 64 + lane];
    float sq = q0 * q0 + q1 * q1;
    float sk = k0 * k0 + k1 * k1;
#pragma unroll
    for (int off = 32; off >= 1; off >>= 1) {
        sq += __shfl_xor(sq, off);
        sk += __shfl_xor(sk, off);
    }
    const float qs = rsqrtf(sq + 1e-6f) * 0.08838834764831845f;
    const float ks = rsqrtf(sk + 1e-6f);
    Qb[base + lane] = q0 * qs; Qb[base + 64 + lane] = q1 * qs;
    Kb[base + lane] = k0 * ks; Kb[base + 64 + lane] = k1 * ks;

    const float a = __expf(A_log[hh]);
    float x0 = Gb[base + lane]      + dt_bias[hh * 128 + lane];
    float x1 = Gb[base + 64 + lane] + dt_bias[hh * 128 + 64 + lane];
    float sp0 = (x0 > 20.f) ? x0 : log1pf(__expf(x0));
    float sp1 = (x1 > 20.f) ? x1 : log1pf(__expf(x1));
    Gb[base + lane]      = __expf(-a * sp0);
    Gb[base + 64 + lane] = __expf(-a * sp1);
}

// --------------------- gated delta-rule sequential scan ---------------------
// v12b: 2048 blocks = (vg 0..63) x (bh 0..31); 1 wave; 2 waves/SIMD resident.
// Column = row-parity: col = (lane>>4)&1; sl = (lane&15) | (((lane>>5)&1)<<4);
// s[4]/lane. Reduce: rsum16 (DPP, row-confined) + crosssum32 (permlane32_swap
// builtin). Triple-buffered LDS, static indices, read-first, chunk-permuted
// staging, depth-2-step FIFO, no-clamp tail — all R13-proven.
__global__ __launch_bounds__(64, 2) void kda_scan(
    const float* __restrict__ Q, const float* __restrict__ Kk,
    const float* __restrict__ V, const float* __restrict__ EG,
    const float* __restrict__ Braw, float* __restrict__ O)
{
    constexpr int T = 2048, H = 16, HD = 2048;
    const int bid = blockIdx.x;
    const int bh  = bid & 31;          // all 64 vg-blocks of a stream -> one XCD
    const int vg  = bid >> 5;          // 0..63
    const int b = bh >> 4, hh = bh & 15;
    const int lane = threadIdx.x;
    const int col  = (lane >> 4) & 1;                        // 0..1
    const int sl   = (lane & 15) | (((lane >> 5) & 1) << 4); // 0..31
    const int vcol = vg * 2 + col;

    __shared__ __align__(16) float k_s[3][128];
    __shared__ __align__(16) float e_s[3][128];
    __shared__ __align__(16) float q_s[3][128];

    float s[4];
#pragma unroll
    for (int i = 0; i < 4; ++i) s[i] = 0.f;

    const size_t tok0 = (size_t)b * T;
    const int cb = hh * 128;
    const float* qp = Q  + tok0 * HD + cb;
    const float* kp = Kk + tok0 * HD + cb;
    const float* ep = EG + tok0 * HD + cb;
    const float* vp = V  + tok0 * HD + cb;
    const float* bp = Braw + tok0 * H + hh;
    float* op = O + tok0 * HD + cb;

    // staging write position (chunk-permuted, proven layout)
    const int d0 = 2 * lane;
    const int cw = lane >> 1;
    const int pw = cw ^ (cw >> 3);
    const int stpos = pw * 4 + (d0 & 3);

    // read offset: this lane's k-slice = 16B chunk sl, at permuted position
    const int rof = (sl ^ (sl >> 3)) << 2;

    // ---- prologue: buf0 <- t=0, buf1 <- t=1; FIFO Fa <- t=2, Fb <- t=3
    {
        *(float2*)&k_s[0][stpos] = *(const float2*)&kp[d0];
        *(float2*)&e_s[0][stpos] = *(const float2*)&ep[d0];
        *(float2*)&q_s[0][stpos] = *(const float2*)&qp[d0];
        *(float2*)&k_s[1][stpos] = *(const float2*)&kp[HD + d0];
        *(float2*)&e_s[1][stpos] = *(const float2*)&ep[HD + d0];
        *(float2*)&q_s[1][stpos] = *(const float2*)&qp[HD + d0];
    }
    float2 FaK = *(const float2*)&kp[(size_t)2 * HD + d0];
    float2 FaE = *(const float2*)&ep[(size_t)2 * HD + d0];
    float2 FaQ = *(const float2*)&qp[(size_t)2 * HD + d0];
    float2 FbK = *(const float2*)&kp[(size_t)3 * HD + d0];
    float2 FbE = *(const float2*)&ep[(size_t)3 * HD + d0];
    float2 FbQ = *(const float2*)&qp[(size_t)3 * HD + d0];
    float v0 = vp[vcol];
    float v1 = vp[(size_t)1 * HD + vcol];
    float v2 = vp[(size_t)2 * HD + vcol];
    float v3 = vp[(size_t)3 * HD + vcol];
    float beta = 1.f / (1.f + __expf(-bp[0]));
    float br1 = bp[(size_t)1 * H];
    float br2 = bp[(size_t)2 * H];
    float br3 = bp[(size_t)3 * H];

    __syncthreads();   // one-time: prologue LDS writes visible before reads

    // frag X <- buf0 (t=0); single float4 per array
    float4 KX, EX, QX, KY, EY, QY;
    KX = *(const float4*)&k_s[0][rof];
    EX = *(const float4*)&e_s[0][rof];
    QX = *(const float4*)&q_s[0][rof];

    auto step = [&](auto bi, const int t,
                    float4& KF, float4& EF, float4& QF,
                    float4& KG, float4& EGr, float4& QG,
                    float2& Fk, float2& Fe, float2& Fq) {
        constexpr int W = decltype(bi)::w;
        constexpr int R = decltype(bi)::r;
        // 1) reads FIRST (data written one full step ago)
        KG  = *(const float4*)&k_s[R][rof];
        EGr = *(const float4*)&e_s[R][rof];
        QG  = *(const float4*)&q_s[R][rof];
        // 2) stage FIFO-held data(t+2) into buf W (read at step t+1)
        *(float2*)&k_s[W][stpos] = Fk;
        *(float2*)&e_s[W][stpos] = Fe;
        *(float2*)&q_s[W][stpos] = Fq;
        // 3) refill FIFO with data(t+4) — no clamp (bounded safe over-read)
        {
            const size_t o4 = (size_t)(t + 4) * HD;
            Fk = *(const float2*)&kp[o4 + d0];
            Fe = *(const float2*)&ep[o4 + d0];
            Fq = *(const float2*)&qp[o4 + d0];
        }
        // 4) pass 1: decay + in-slice k.s
        float s0 = s[0] * EF.x, s1 = s[1] * EF.y;
        float s2 = s[2] * EF.z, s3 = s[3] * EF.w;
        s[0] = s0; s[1] = s1; s[2] = s2; s[3] = s3;
        float a0 = KF.x * s0, a1 = KF.y * s1;
        float a2 = KF.z * s2, a3 = KF.w * s3;
        float kS = crosssum32(rsum16((a0 + a1) + (a2 + a3)));
        const float delta = beta * (v0 - kS);
        // 5) pass 2: rank-1 update + in-slice q.s
        float t0v = fmaf(KF.x, delta, s[0]);
        float t1v = fmaf(KF.y, delta, s[1]);
        float t2v = fmaf(KF.z, delta, s[2]);
        float t3v = fmaf(KF.w, delta, s[3]);
        s[0] = t0v; s[1] = t1v; s[2] = t2v; s[3] = t3v;
        float o0 = QF.x * t0v, o1 = QF.y * t1v;
        float o2v = QF.z * t2v, o3v = QF.w * t3v;
        float oo = crosssum32(rsum16((o0 + o1) + (o2v + o3v)));
        if (sl == 0) op[(size_t)t * HD + vcol] = oo;
        // 6) v/beta FIFO shift; load data(t+4) — no clamp
        {
            const float vn = vp[(size_t)(t + 4) * HD + vcol];
            const float bn = bp[(size_t)(t + 4) * H];
            v0 = v1; v1 = v2; v2 = v3; v3 = vn;
            beta = 1.f / (1.f + __expf(-br1));
            br1 = br2; br2 = br3; br3 = bn;
        }
    };

    // wbuf cycle (start 2): 2,0,1,...  rbuf cycle (start 1): 1,2,0,...
    // frag cycle: X,Y,X,Y,...  combined period 6; T = 6*341 + 2.
    for (int t = 0; t < T - 2; t += 6) {
        step(BufIdx<2, 1>{}, t + 0, KX, EX, QX, KY, EY, QY, FaK, FaE, FaQ);
        step(BufIdx<0, 2>{}, t + 1, KY, EY, QY, KX, EX, QX, FbK, FbE, FbQ);
        step(BufIdx<1, 0>{}, t + 2, KX, EX, QX, KY, EY, QY, FaK, FaE, FaQ);
        step(BufIdx<2, 1>{}, t + 3, KY, EY, QY, KX, EX, QX, FbK, FbE, FbQ);
        step(BufIdx<0, 2>{}, t + 4, KX, EX, QX, KY, EY, QY, FaK, FaE, FaQ);
        step(BufIdx<1, 0>{}, t + 5, KY, EY, QY, KX, EX, QX, FbK, FbE, FbQ);
    }
    step(BufIdx<2, 1>{}, T - 2, KX, EX, QX, KY, EY, QY, FaK, FaE, FaQ);
    step(BufIdx<0, 2>{}, T - 1, KY, EY, QY, KX, EX, QX, FbK, FbE, FbQ);
}

// ------ gated RMSNorm: obf16 = rms(o)*norm_w*sigmoid(gate), bf16 out --------
__global__ __launch_bounds__(256) void norm_gate(
    const float* __restrict__ O, const float* __restrict__ Gate,
    const float* __restrict__ norm_w, ushort* __restrict__ Out16, int rows)
{
    const int wave = threadIdx.x >> 6;
    const int lane = threadIdx.x & 63;
    const int row  = blockIdx.x * 4 + wave;
    if (row >= rows) return;
    const size_t base = (size_t)row * 128;

    float o0 = O[base + lane], o1 = O[base + 64 + lane];
    float ss = o0 * o0 + o1 * o1;
#pragma unroll
    for (int off = 32; off >= 1; off >>= 1) ss += __shfl_xor(ss, off);
    const float scale = rsqrtf(ss * (1.f / 128.f) + 1e-6f);

    const float g0 = Gate[base + lane], g1 = Gate[base + 64 + lane];
    o0 = o0 * scale * norm_w[lane]      * (1.f / (1.f + __expf(-g0)));
    o1 = o1 * scale * norm_w[64 + lane] * (1.f / (1.f + __expf(-g1)));
    Out16[base + lane]      = f2bf(o0);
    Out16[base + 64 + lane] = f2bf(o1);
}

// ---------------------------------------------------------------------------
extern "C" void kernel_launch(void* const* d_in, const int* in_sizes, int n_in,
                              void* d_out, int out_size, void* d_ws, size_t ws_size,
                              hipStream_t stream)
{
    const float* h    = (const float*)d_in[0];
    const float* Wq   = (const float*)d_in[1];
    const float* Wk   = (const float*)d_in[2];
    const float* Wv   = (const float*)d_in[3];
    const float* cwq  = (const float*)d_in[4];
    const float* cwk  = (const float*)d_in[5];
    const float* cwv  = (const float*)d_in[6];
    const float* A_log= (const float*)d_in[7];
    const float* dtb  = (const float*)d_in[8];
    const float* Wfa  = (const float*)d_in[9];
    const float* Wfb  = (const float*)d_in[10];
    const float* Wb   = (const float*)d_in[11];
    const float* Wga  = (const float*)d_in[12];
    const float* Wgb  = (const float*)d_in[13];
    const float* nw   = (const float*)d_in[14];
    const float* Wo   = (const float*)d_in[15];
    float* out = (float*)d_out;

    const int M = 4096, HID = 2048;
    const size_t big = (size_t)M * HID;        // 8M elements
    float* ws    = (float*)d_ws;
    float* qb    = ws;          // post-scan: gateb
    float* kb    = qb + big;
    float* vb    = kb + big;    // post-norm: obb16 (ushort)
    float* gb    = vb + big;
    float* ob    = gb + big;
    float* betab = ob + big;                        // 4096x16
    float* halb  = betab + (size_t)M * 16;          // 110592
    ushort* hb16 = (ushort*)(halb + 110592);        // [M,HID] bf16
    ushort* wqT  = hb16 + big;                      // [2048,2048] bf16 (x4)
    ushort* wkT  = wqT + (size_t)HID * HID;
    ushort* wvT  = wkT + (size_t)HID * HID;
    ushort* wfT  = wvT + (size_t)HID * HID;
    ushort* tfbT = wfT + (size_t)HID * HID;         // [2048,128] bf16
    ushort* wfa16= tfbT + (size_t)HID * 128;        // [2048,128] bf16

    float*  gateb = qb;
    ushort* obb16 = (ushort*)vb;

    dim3 blk(256);

    // bf16 casts / transposes
    cast_bf16<<<dim3(4096), blk, 0, stream>>>(h, hb16, (int)(big / 8));
    tcast<<<dim3(32, 32), blk, 0, stream>>>(Wq, wqT, HID, HID);
    tcast<<<dim3(32, 32), blk, 0, stream>>>(Wk, wkT, HID, HID);
    tcast<<<dim3(32, 32), blk, 0, stream>>>(Wv, wvT, HID, HID);

    // compose Wf = Wfa@Wfb in bf16 MFMA: wfT[m,n] = sum_k Wfb[k,m]*Wfa[n,k]
    tcast<<<dim3(32, 2), blk, 0, stream>>>(Wfb, tfbT, 128, HID);
    cast_bf16<<<dim3(128), blk, 0, stream>>>(Wfa, wfa16, (int)((size_t)HID * 128 / 8));
    gemm_bf16<true><<<dim3(16, 16, 1), blk, 0, stream>>>(
        tfbT, tfbT, tfbT, tfbT, wfa16, wfa16, wfa16, wfa16,
        wfT, wfT, wfT, wfT, HID, HID, 128);

    // q,k,v,g projections in ONE launch
    gemm_bf16<false><<<dim3(32, 16, 4), blk, 0, stream>>>(
        hb16, hb16, hb16, hb16, wqT, wkT, wvT, wfT,
        qb, kb, vb, gb, M, HID, HID);

    // beta
    gemm_n16<<<dim3(M / 16), blk, 0, stream>>>(h, Wb, betab, M, HID);

    // conv + SiLU (segmented, race-free via halo snapshot)
    halo_save<<<dim3(432), blk, 0, stream>>>(qb, kb, vb, halb);
    conv_silu<<<dim3(192), blk, 0, stream>>>(qb, kb, vb, cwq, cwk, cwv, halb);

    // l2norm q/k, g -> exp(g)
    prep_qkg<<<dim3(16384), blk, 0, stream>>>(qb, kb, gb, A_log, dtb, M * 16);

    // gated delta-rule scan (2048 blocks: 2 waves per SIMD)
    kda_scan<<<dim3(2048), dim3(64), 0, stream>>>(qb, kb, vb, gb, betab, ob);

    // gate path: compose Wg = Wga@Wgb (bf16 MFMA, reuse small scratch + wqT)
    tcast<<<dim3(32, 2), blk, 0, stream>>>(Wgb, tfbT, 128, HID);
    cast_bf16<<<dim3(128), blk, 0, stream>>>(Wga, wfa16, (int)((size_t)HID * 128 / 8));
    gemm_bf16<true><<<dim3(16, 16, 1), blk, 0, stream>>>(
        tfbT, tfbT, tfbT, tfbT, wfa16, wfa16, wfa16, wfa16,
        wqT, wqT, wqT, wqT, HID, HID, 128);
    gemm_bf16<false><<<dim3(32, 16, 1), blk, 0, stream>>>(
        hb16, hb16, hb16, hb16, wqT, wqT, wqT, wqT,
        gateb, gateb, gateb, gateb, M, HID, HID);

    // gated RMSNorm -> bf16 (fused cast)
    norm_gate<<<dim3(16384), blk, 0, stream>>>(ob, gateb, nw, obb16, M * 16);

    // output projection
    tcast<<<dim3(32, 32), blk, 0, stream>>>(Wo, wkT, HID, HID);
    gemm_bf16<false><<<dim3(32, 16, 1), blk, 0, stream>>>(
        obb16, obb16, obb16, obb16, wkT, wkT, wkT, wkT,
        out, out, out, out, M, HID, HID);
}

// Round 16
// 1199.510 us; speedup vs baseline: 1.0928x; 1.0928x over previous
//
#include <hip/hip_runtime.h>
#include <hip/hip_bf16.h>

// ---------------------------------------------------------------------------
// KimiDeltaAttention — round 16.
//  * scan: exact R13 kernel (1024 blocks, s[8]/lane, rsum16 DPP, static
//    triple-buffer) — proven 784 us; R15's 2-wave variant regressed (issue-
//    bound crossover) and is reverted.
//  * gemm_bf16: staging via __builtin_amdgcn_global_load_lds width=16.
//    LDS dest linear (HW base+lane*16); XOR swizzle moved to per-lane global
//    source chunk c = (lane&7)^(lane>>3) — same involution the read side
//    applies (row&7 == lane>>3 per 8-row group). Read path unchanged.
// ---------------------------------------------------------------------------

using short8 = __attribute__((ext_vector_type(8))) short;
using f32x4  = __attribute__((ext_vector_type(4))) float;

static __device__ __forceinline__ ushort f2bf(float f) {
    __hip_bfloat16 h = __float2bfloat16(f);
    return *reinterpret_cast<ushort*>(&h);
}

// DPP butterfly/rotation adds (VALU-speed, no LDS pipe)
static __device__ __forceinline__ float qadd1(float x) {   // lane ^= 1 (quad)
    int y = __builtin_amdgcn_mov_dpp(__float_as_int(x), 0xB1, 0xF, 0xF, true);
    return x + __int_as_float(y);
}
static __device__ __forceinline__ float qadd2(float x) {   // lane ^= 2 (quad)
    int y = __builtin_amdgcn_mov_dpp(__float_as_int(x), 0x4E, 0xF, 0xF, true);
    return x + __int_as_float(y);
}
static __device__ __forceinline__ float radd4(float x) {   // row_ror:4
    int y = __builtin_amdgcn_mov_dpp(__float_as_int(x), 0x124, 0xF, 0xF, true);
    return x + __int_as_float(y);
}
static __device__ __forceinline__ float radd8(float x) {   // row_ror:8
    int y = __builtin_amdgcn_mov_dpp(__float_as_int(x), 0x128, 0xF, 0xF, true);
    return x + __int_as_float(y);
}
// full sum across a 16-lane row, result in every lane of the row
static __device__ __forceinline__ float rsum16(float x) {
    x = qadd1(x);
    x = qadd2(x);
    x = radd4(x);
    x = radd8(x);
    return x;
}

template<int W, int R> struct BufIdx { static constexpr int w = W, r = R; };

// ----------------------- row-major f32 -> bf16 cast -------------------------
__global__ __launch_bounds__(256) void cast_bf16(const float* __restrict__ in,
                                                 ushort* __restrict__ out, int n8)
{
    const int i = blockIdx.x * 256 + threadIdx.x;
    if (i >= n8) return;
    const float4 a = ((const float4*)in)[2 * i];
    const float4 b = ((const float4*)in)[2 * i + 1];
    ushort u[8] = {f2bf(a.x), f2bf(a.y), f2bf(a.z), f2bf(a.w),
                   f2bf(b.x), f2bf(b.y), f2bf(b.z), f2bf(b.w)};
    ((uint4*)out)[i] = *(uint4*)u;
}

// ------------------- transpose-cast: f32 [R,C] -> bf16 [C,R] ----------------
__global__ __launch_bounds__(256) void tcast(const float* __restrict__ in,
                                             ushort* __restrict__ out,
                                             int R, int C)
{
    __shared__ float tile[64][68];
    const int t  = threadIdx.x;
    const int c0 = blockIdx.x * 64, r0 = blockIdx.y * 64;
    const int lr = t >> 2, lc = (t & 3) * 16;
#pragma unroll
    for (int j = 0; j < 4; ++j) {
        const float4 v = *(const float4*)&in[(size_t)(r0 + lr) * C + c0 + lc + 4 * j];
        *(float4*)&tile[lr][lc + 4 * j] = v;
    }
    __syncthreads();
    const int oc = t >> 2, och = (t & 3) * 16;
    uint u[8];
#pragma unroll
    for (int j = 0; j < 8; ++j) {
        const float f0 = tile[och + 2 * j][oc];
        const float f1 = tile[och + 2 * j + 1][oc];
        u[j] = (uint)f2bf(f0) | ((uint)f2bf(f1) << 16);
    }
    uint4* dst = (uint4*)&out[(size_t)(c0 + oc) * R + r0 + och];
    dst[0] = make_uint4(u[0], u[1], u[2], u[3]);
    dst[1] = make_uint4(u[4], u[5], u[6], u[7]);
}

// --------------- bf16 MFMA GEMM: C[M,N] = A[M,K] @ Bt[N,K]^T ----------------
// 128x128 tile, BK=64, 4 waves (2x2). Staging: global_load_lds width=16,
// linear LDS dest, pre-swizzled global source (chunk c = (lane&7)^(lane>>3)).
template<bool OUT16>
__global__ __launch_bounds__(256) void gemm_bf16(
    const ushort* __restrict__ A0, const ushort* __restrict__ A1,
    const ushort* __restrict__ A2, const ushort* __restrict__ A3,
    const ushort* __restrict__ B0, const ushort* __restrict__ B1,
    const ushort* __restrict__ B2, const ushort* __restrict__ B3,
    void* __restrict__ C0, void* __restrict__ C1,
    void* __restrict__ C2, void* __restrict__ C3,
    int M, int N, int K)
{
    const int z = blockIdx.z;
    const ushort* A = (z == 0) ? A0 : (z == 1) ? A1 : (z == 2) ? A2 : A3;
    const ushort* B = (z == 0) ? B0 : (z == 1) ? B1 : (z == 2) ? B2 : B3;
    void* Cv       = (z == 0) ? C0 : (z == 1) ? C1 : (z == 2) ? C2 : C3;

    __shared__ ushort As[128 * 64];
    __shared__ ushort Bs[128 * 64];

    const int tid  = threadIdx.x;
    const int lane = tid & 63;
    const int wave = tid >> 6;
    const int wm = wave >> 1, wn = wave & 1;
    const int bm = blockIdx.x * 128, bn = blockIdx.y * 128;

    const int ml = lane & 15;
    const int g  = lane >> 4;

    // gload_lds source offsets: lane covers row (8-group) lrow, swizzled chunk
    const int lrow = lane >> 3;                  // 0..7
    const int cofs = ((lane & 7) ^ lrow) * 8;    // ushort offset of 16B chunk

    f32x4 acc[4][4];
#pragma unroll
    for (int i = 0; i < 4; ++i)
#pragma unroll
        for (int j = 0; j < 4; ++j) acc[i][j] = (f32x4){0.f, 0.f, 0.f, 0.f};

    for (int k0 = 0; k0 < K; k0 += 64) {
        // wave w stages rows [w*32, w*32+32) of A-tile and B-tile:
        // 4 async 1KB instructions each, LDS linear, source pre-swizzled.
#pragma unroll
        for (int i = 0; i < 4; ++i) {
            const int row = wave * 32 + i * 8 + lrow;
            const ushort* gA = A + (size_t)(bm + row) * K + k0 + cofs;
            const ushort* gB = B + (size_t)(bn + row) * K + k0 + cofs;
            ushort* lA = As + (wave * 32 + i * 8) * 64;
            ushort* lB = Bs + (wave * 32 + i * 8) * 64;
            __builtin_amdgcn_global_load_lds(
                (const __attribute__((address_space(1))) void*)gA,
                (__attribute__((address_space(3))) void*)lA, 16, 0, 0);
            __builtin_amdgcn_global_load_lds(
                (const __attribute__((address_space(1))) void*)gB,
                (__attribute__((address_space(3))) void*)lB, 16, 0, 0);
        }
        __syncthreads();
#pragma unroll
        for (int kk = 0; kk < 2; ++kk) {
            short8 af[4], bfr[4];
#pragma unroll
            for (int mi = 0; mi < 4; ++mi) {
                const int row = wm * 64 + mi * 16 + ml;
                const int sw  = ((row * 128 + (kk * 4 + g) * 16) ^ ((ml & 7) << 4)) >> 1;
                af[mi] = *(const short8*)&As[sw];
            }
#pragma unroll
            for (int ni = 0; ni < 4; ++ni) {
                const int row = wn * 64 + ni * 16 + ml;
                const int sw  = ((row * 128 + (kk * 4 + g) * 16) ^ ((ml & 7) << 4)) >> 1;
                bfr[ni] = *(const short8*)&Bs[sw];
            }
#pragma unroll
            for (int mi = 0; mi < 4; ++mi)
#pragma unroll
                for (int ni = 0; ni < 4; ++ni)
                    acc[mi][ni] = __builtin_amdgcn_mfma_f32_16x16x32_bf16(
                        af[mi], bfr[ni], acc[mi][ni], 0, 0, 0);
        }
        __syncthreads();
    }

#pragma unroll
    for (int mi = 0; mi < 4; ++mi)
#pragma unroll
        for (int ni = 0; ni < 4; ++ni) {
            const int col = bn + wn * 64 + ni * 16 + ml;
#pragma unroll
            for (int r = 0; r < 4; ++r) {
                const int row = bm + wm * 64 + mi * 16 + g * 4 + r;
                if constexpr (OUT16) {
                    ((ushort*)Cv)[(size_t)row * N + col] = f2bf(acc[mi][ni][r]);
                } else {
                    ((float*)Cv)[(size_t)row * N + col] = acc[mi][ni][r];
                }
            }
        }
}

// ------------------- small-N GEMM for beta: N = 16 -------------------------
__global__ __launch_bounds__(256) void gemm_n16(
    const float* __restrict__ A, const float* __restrict__ B,
    float* __restrict__ C, int M, int Kd)
{
    const int tid  = threadIdx.x;
    const int n    = tid & 15;
    const int mloc = tid >> 4;
    const int m    = blockIdx.x * 16 + mloc;
    const float* a  = A + (size_t)m * Kd;
    const float* bn = B + n;
    float acc = 0.f;
#pragma unroll 4
    for (int k0 = 0; k0 < Kd; k0 += 8) {
        float4 a0 = *(const float4*)(a + k0);
        float4 a1 = *(const float4*)(a + k0 + 4);
        acc = fmaf(a0.x, bn[(size_t)(k0 + 0) * 16], acc);
        acc = fmaf(a0.y, bn[(size_t)(k0 + 1) * 16], acc);
        acc = fmaf(a0.z, bn[(size_t)(k0 + 2) * 16], acc);
        acc = fmaf(a0.w, bn[(size_t)(k0 + 3) * 16], acc);
        acc = fmaf(a1.x, bn[(size_t)(k0 + 4) * 16], acc);
        acc = fmaf(a1.y, bn[(size_t)(k0 + 5) * 16], acc);
        acc = fmaf(a1.z, bn[(size_t)(k0 + 6) * 16], acc);
        acc = fmaf(a1.w, bn[(size_t)(k0 + 7) * 16], acc);
    }
    C[(size_t)m * 16 + n] = acc;
}

// ---- halo save: pre-conv values at segment boundaries (race-free split) ----
__global__ __launch_bounds__(256) void halo_save(
    const float* __restrict__ q, const float* __restrict__ k,
    const float* __restrict__ v, float* __restrict__ hal)
{
    constexpr int T = 2048, C = 2048, SEG = 512;
    const int idx = blockIdx.x * 256 + threadIdx.x;   // < 9*12288
    const int cid = idx % 12288;
    const int sh  = idx / 12288;      // 0..8
    const int sg  = sh / 3 + 1;       // segment 1..3
    const int ho  = sh % 3;           // halo offset 0..2
    const int which = cid >> 12, rem = cid & 4095, b = rem >> 11, c = rem & 2047;
    const float* x = (which == 0) ? q : (which == 1) ? k : v;
    hal[idx] = x[(size_t)b * T * C + (size_t)(sg * SEG - 3 + ho) * C + c];
}

// ------- depthwise causal conv (K=4) + SiLU, in-place, 4 T-segments ---------
__global__ __launch_bounds__(256) void conv_silu(
    float* __restrict__ q, float* __restrict__ k, float* __restrict__ v,
    const float* __restrict__ wq, const float* __restrict__ wk,
    const float* __restrict__ wv, const float* __restrict__ hal)
{
    constexpr int T = 2048, C = 2048, SEG = 512;
    const int seg    = blockIdx.x & 3;
    const int colblk = blockIdx.x >> 2;
    const int cid    = colblk * 256 + threadIdx.x;
    const int which  = cid >> 12;
    const int rem    = cid & 4095;
    const int b      = rem >> 11;
    const int c      = rem & 2047;
    float* x        = (which == 0) ? q : (which == 1) ? k : v;
    const float* w  = (which == 0) ? wq : (which == 1) ? wk : wv;

    const float w0 = w[c * 4 + 0], w1 = w[c * 4 + 1];
    const float w2 = w[c * 4 + 2], w3 = w[c * 4 + 3];
    float* p = x + (size_t)b * T * C + c;
    float xm3, xm2, xm1;
    if (seg == 0) { xm3 = xm2 = xm1 = 0.f; }
    else {
        xm3 = hal[((seg - 1) * 3 + 0) * 12288 + cid];
        xm2 = hal[((seg - 1) * 3 + 1) * 12288 + cid];
        xm1 = hal[((seg - 1) * 3 + 2) * 12288 + cid];
    }

    const int t0s = seg * SEG;
    for (int t0 = t0s; t0 < t0s + SEG; t0 += 16) {
        float xt[16], yo[16];
#pragma unroll
        for (int j = 0; j < 16; ++j) xt[j] = p[(size_t)(t0 + j) * C];
#pragma unroll
        for (int j = 0; j < 16; ++j) {
            float y = fmaf(xm3, w0, fmaf(xm2, w1, fmaf(xm1, w2, xt[j] * w3)));
            yo[j] = y / (1.f + __expf(-y));
            xm3 = xm2; xm2 = xm1; xm1 = xt[j];
        }
#pragma unroll
        for (int j = 0; j < 16; ++j) p[(size_t)(t0 + j) * C] = yo[j];
    }
}

// ------ prep: l2norm(q)*D^-0.5, l2norm(k), g -> exp(-exp(A_log)*softplus) ---
__global__ __launch_bounds__(256) void prep_qkg(
    float* __restrict__ Qb, float* __restrict__ Kb, float* __restrict__ Gb,
    const float* __restrict__ A_log, const float* __restrict__ dt_bias,
    int rows)
{
    const int wave = threadIdx.x >> 6;
    const int lane = threadIdx.x & 63;
    const int row  = blockIdx.x * 4 + wave;
    if (row >= rows) return;
    const int hh = row & 15;
    const size_t base = (size_t)row * 128;

    float q0 = Qb[base + lane], q1 = Qb[base + 64 + lane];
    float k0 = Kb[base + lane], k1 = Kb[base + 64 + lane];
    float sq = q0 * q0 + q1 * q1;
    float sk = k0 * k0 + k1 * k1;
#pragma unroll
    for (int off = 32; off >= 1; off >>= 1) {
        sq += __shfl_xor(sq, off);
        sk += __shfl_xor(sk, off);
    }
    const float qs = rsqrtf(sq + 1e-6f) * 0.08838834764831845f;
    const float ks = rsqrtf(sk + 1e-6f);
    Qb[base + lane] = q0 * qs; Qb[base + 64 + lane] = q1 * qs;
    Kb[base + lane] = k0 * ks; Kb[base + 64 + lane] = k1 * ks;

    const float a = __expf(A_log[hh]);
    float x0 = Gb[base + lane]      + dt_bias[hh * 128 + lane];
    float x1 = Gb[base + 64 + lane] + dt_bias[hh * 128 + 64 + lane];
    float sp0 = (x0 > 20.f) ? x0 : log1pf(__expf(x0));
    float sp1 = (x1 > 20.f) ? x1 : log1pf(__expf(x1));
    Gb[base + lane]      = __expf(-a * sp0);
    Gb[base + 64 + lane] = __expf(-a * sp1);
}

// --------------------- gated delta-rule sequential scan ---------------------
// R13-proven: 1024 blocks = (vg 0..31) x (bh 0..31); 1 wave; lane = (col 0..3,
// sl 0..15); s[8]/lane; DPP rsum16 reductions. Triple-buffered LDS with
// compile-time buffer indices (loop unrolled x6), frag reads issued before
// staging writes, no tail clamps (bounded safe over-read).
__global__ __launch_bounds__(64, 1) void kda_scan(
    const float* __restrict__ Q, const float* __restrict__ Kk,
    const float* __restrict__ V, const float* __restrict__ EG,
    const float* __restrict__ Braw, float* __restrict__ O)
{
    constexpr int T = 2048, H = 16, HD = 2048;
    const int bid = blockIdx.x;
    const int bh  = bid & 31;
    const int vg  = bid >> 5;          // 0..31
    const int b = bh >> 4, hh = bh & 15;
    const int lane = threadIdx.x;
    const int col  = lane >> 4;        // 0..3
    const int sl   = lane & 15;        // 0..15
    const int vcol = vg * 4 + col;

    __shared__ __align__(16) float k_s[3][128];
    __shared__ __align__(16) float e_s[3][128];
    __shared__ __align__(16) float q_s[3][128];

    float s[8];
#pragma unroll
    for (int i = 0; i < 8; ++i) s[i] = 0.f;

    const size_t tok0 = (size_t)b * T;
    const int cb = hh * 128;
    const float* qp = Q  + tok0 * HD + cb;
    const float* kp = Kk + tok0 * HD + cb;
    const float* ep = EG + tok0 * HD + cb;
    const float* vp = V  + tok0 * HD + cb;
    const float* bp = Braw + tok0 * H + hh;
    float* op = O + tok0 * HD + cb;

    const int d0 = 2 * lane;
    const int cw = lane >> 1;
    const int pw = cw ^ (cw >> 3);
    const int stpos = pw * 4 + (d0 & 3);

    const int c0r = 2 * sl, c1r = 2 * sl + 1;
    const int rof0 = (c0r ^ (c0r >> 3)) << 2;
    const int rof1 = (c1r ^ (c1r >> 3)) << 2;

    {
        *(float2*)&k_s[0][stpos] = *(const float2*)&kp[d0];
        *(float2*)&e_s[0][stpos] = *(const float2*)&ep[d0];
        *(float2*)&q_s[0][stpos] = *(const float2*)&qp[d0];
        *(float2*)&k_s[1][stpos] = *(const float2*)&kp[HD + d0];
        *(float2*)&e_s[1][stpos] = *(const float2*)&ep[HD + d0];
        *(float2*)&q_s[1][stpos] = *(const float2*)&qp[HD + d0];
    }
    float2 FaK = *(const float2*)&kp[(size_t)2 * HD + d0];
    float2 FaE = *(const float2*)&ep[(size_t)2 * HD + d0];
    float2 FaQ = *(const float2*)&qp[(size_t)2 * HD + d0];
    float2 FbK = *(const float2*)&kp[(size_t)3 * HD + d0];
    float2 FbE = *(const float2*)&ep[(size_t)3 * HD + d0];
    float2 FbQ = *(const float2*)&qp[(size_t)3 * HD + d0];
    float v0 = vp[vcol];
    float v1 = vp[(size_t)1 * HD + vcol];
    float v2 = vp[(size_t)2 * HD + vcol];
    float v3 = vp[(size_t)3 * HD + vcol];
    float beta = 1.f / (1.f + __expf(-bp[0]));
    float br1 = bp[(size_t)1 * H];
    float br2 = bp[(size_t)2 * H];
    float br3 = bp[(size_t)3 * H];

    __syncthreads();

    float4 KX[2], EX[2], QX[2], KY[2], EY[2], QY[2];
    KX[0] = *(const float4*)&k_s[0][rof0];
    KX[1] = *(const float4*)&k_s[0][rof1];
    EX[0] = *(const float4*)&e_s[0][rof0];
    EX[1] = *(const float4*)&e_s[0][rof1];
    QX[0] = *(const float4*)&q_s[0][rof0];
    QX[1] = *(const float4*)&q_s[0][rof1];

    auto step = [&](auto bi, const int t,
                    float4* KF, float4* EF, float4* QF,
                    float4* KG, float4* EGr, float4* QG,
                    float2& Fk, float2& Fe, float2& Fq) {
        constexpr int W = decltype(bi)::w;
        constexpr int R = decltype(bi)::r;
        KG[0]  = *(const float4*)&k_s[R][rof0];
        KG[1]  = *(const float4*)&k_s[R][rof1];
        EGr[0] = *(const float4*)&e_s[R][rof0];
        EGr[1] = *(const float4*)&e_s[R][rof1];
        QG[0]  = *(const float4*)&q_s[R][rof0];
        QG[1]  = *(const float4*)&q_s[R][rof1];
        *(float2*)&k_s[W][stpos] = Fk;
        *(float2*)&e_s[W][stpos] = Fe;
        *(float2*)&q_s[W][stpos] = Fq;
        {
            const size_t o4 = (size_t)(t + 4) * HD;
            Fk = *(const float2*)&kp[o4 + d0];
            Fe = *(const float2*)&ep[o4 + d0];
            Fq = *(const float2*)&qp[o4 + d0];
        }
        float a0, a1, a2, a3;
        {
            float s0 = s[0] * EF[0].x, s1 = s[1] * EF[0].y;
            float s2 = s[2] * EF[0].z, s3 = s[3] * EF[0].w;
            float s4 = s[4] * EF[1].x, s5 = s[5] * EF[1].y;
            float s6 = s[6] * EF[1].z, s7 = s[7] * EF[1].w;
            s[0] = s0; s[1] = s1; s[2] = s2; s[3] = s3;
            s[4] = s4; s[5] = s5; s[6] = s6; s[7] = s7;
            a0 = KF[0].x * s0; a1 = KF[0].y * s1;
            a2 = KF[0].z * s2; a3 = KF[0].w * s3;
            a0 = fmaf(KF[1].x, s4, a0); a1 = fmaf(KF[1].y, s5, a1);
            a2 = fmaf(KF[1].z, s6, a2); a3 = fmaf(KF[1].w, s7, a3);
        }
        float kS = rsum16((a0 + a1) + (a2 + a3));
        const float delta = beta * (v0 - kS);
        float o0, o1, o2v, o3v;
        {
            float s0 = fmaf(KF[0].x, delta, s[0]);
            float s1 = fmaf(KF[0].y, delta, s[1]);
            float s2 = fmaf(KF[0].z, delta, s[2]);
            float s3 = fmaf(KF[0].w, delta, s[3]);
            float s4 = fmaf(KF[1].x, delta, s[4]);
            float s5 = fmaf(KF[1].y, delta, s[5]);
            float s6 = fmaf(KF[1].z, delta, s[6]);
            float s7 = fmaf(KF[1].w, delta, s[7]);
            s[0] = s0; s[1] = s1; s[2] = s2; s[3] = s3;
            s[4] = s4; s[5] = s5; s[6] = s6; s[7] = s7;
            o0 = QF[0].x * s0; o1 = QF[0].y * s1;
            o2v = QF[0].z * s2; o3v = QF[0].w * s3;
            o0 = fmaf(QF[1].x, s4, o0); o1 = fmaf(QF[1].y, s5, o1);
            o2v = fmaf(QF[1].z, s6, o2v); o3v = fmaf(QF[1].w, s7, o3v);
        }
        float oo = rsum16((o0 + o1) + (o2v + o3v));
        if (sl == 0) op[(size_t)t * HD + vcol] = oo;
        {
            const float vn = vp[(size_t)(t + 4) * HD + vcol];
            const float bn = bp[(size_t)(t + 4) * H];
            v0 = v1; v1 = v2; v2 = v3; v3 = vn;
            beta = 1.f / (1.f + __expf(-br1));
            br1 = br2; br2 = br3; br3 = bn;
        }
    };

    for (int t = 0; t < T - 2; t += 6) {
        step(BufIdx<2, 1>{}, t + 0, KX, EX, QX, KY, EY, QY, FaK, FaE, FaQ);
        step(BufIdx<0, 2>{}, t + 1, KY, EY, QY, KX, EX, QX, FbK, FbE, FbQ);
        step(BufIdx<1, 0>{}, t + 2, KX, EX, QX, KY, EY, QY, FaK, FaE, FaQ);
        step(BufIdx<2, 1>{}, t + 3, KY, EY, QY, KX, EX, QX, FbK, FbE, FbQ);
        step(BufIdx<0, 2>{}, t + 4, KX, EX, QX, KY, EY, QY, FaK, FaE, FaQ);
        step(BufIdx<1, 0>{}, t + 5, KY, EY, QY, KX, EX, QX, FbK, FbE, FbQ);
    }
    step(BufIdx<2, 1>{}, T - 2, KX, EX, QX, KY, EY, QY, FaK, FaE, FaQ);
    step(BufIdx<0, 2>{}, T - 1, KY, EY, QY, KX, EX, QX, FbK, FbE, FbQ);
}

// ------ gated RMSNorm: obf16 = rms(o)*norm_w*sigmoid(gate), bf16 out --------
__global__ __launch_bounds__(256) void norm_gate(
    const float* __restrict__ O, const float* __restrict__ Gate,
    const float* __restrict__ norm_w, ushort* __restrict__ Out16, int rows)
{
    const int wave = threadIdx.x >> 6;
    const int lane = threadIdx.x & 63;
    const int row  = blockIdx.x * 4 + wave;
    if (row >= rows) return;
    const size_t base = (size_t)row * 128;

    float o0 = O[base + lane], o1 = O[base + 64 + lane];
    float ss = o0 * o0 + o1 * o1;
#pragma unroll
    for (int off = 32; off >= 1; off >>= 1) ss += __shfl_xor(ss, off);
    const float scale = rsqrtf(ss * (1.f / 128.f) + 1e-6f);

    const float g0 = Gate[base + lane], g1 = Gate[base + 64 + lane];
    o0 = o0 * scale * norm_w[lane]      * (1.f / (1.f + __expf(-g0)));
    o1 = o1 * scale * norm_w[64 + lane] * (1.f / (1.f + __expf(-g1)));
    Out16[base + lane]      = f2bf(o0);
    Out16[base + 64 + lane] = f2bf(o1);
}

// ---------------------------------------------------------------------------
extern "C" void kernel_launch(void* const* d_in, const int* in_sizes, int n_in,
                              void* d_out, int out_size, void* d_ws, size_t ws_size,
                              hipStream_t stream)
{
    const float* h    = (const float*)d_in[0];
    const float* Wq   = (const float*)d_in[1];
    const float* Wk   = (const float*)d_in[2];
    const float* Wv   = (const float*)d_in[3];
    const float* cwq  = (const float*)d_in[4];
    const float* cwk  = (const float*)d_in[5];
    const float* cwv  = (const float*)d_in[6];
    const float* A_log= (const float*)d_in[7];
    const float* dtb  = (const float*)d_in[8];
    const float* Wfa  = (const float*)d_in[9];
    const float* Wfb  = (const float*)d_in[10];
    const float* Wb   = (const float*)d_in[11];
    const float* Wga  = (const float*)d_in[12];
    const float* Wgb  = (const float*)d_in[13];
    const float* nw   = (const float*)d_in[14];
    const float* Wo   = (const float*)d_in[15];
    float* out = (float*)d_out;

    const int M = 4096, HID = 2048;
    const size_t big = (size_t)M * HID;        // 8M elements
    float* ws    = (float*)d_ws;
    float* qb    = ws;          // post-scan: gateb
    float* kb    = qb + big;
    float* vb    = kb + big;    // post-norm: obb16 (ushort)
    float* gb    = vb + big;
    float* ob    = gb + big;
    float* betab = ob + big;                        // 4096x16
    float* halb  = betab + (size_t)M * 16;          // 110592
    ushort* hb16 = (ushort*)(halb + 110592);        // [M,HID] bf16
    ushort* wqT  = hb16 + big;                      // [2048,2048] bf16 (x4)
    ushort* wkT  = wqT + (size_t)HID * HID;
    ushort* wvT  = wkT + (size_t)HID * HID;
    ushort* wfT  = wvT + (size_t)HID * HID;
    ushort* tfbT = wfT + (size_t)HID * HID;         // [2048,128] bf16
    ushort* wfa16= tfbT + (size_t)HID * 128;        // [2048,128] bf16

    float*  gateb = qb;
    ushort* obb16 = (ushort*)vb;

    dim3 blk(256);

    // bf16 casts / transposes
    cast_bf16<<<dim3(4096), blk, 0, stream>>>(h, hb16, (int)(big / 8));
    tcast<<<dim3(32, 32), blk, 0, stream>>>(Wq, wqT, HID, HID);
    tcast<<<dim3(32, 32), blk, 0, stream>>>(Wk, wkT, HID, HID);
    tcast<<<dim3(32, 32), blk, 0, stream>>>(Wv, wvT, HID, HID);

    // compose Wf = Wfa@Wfb in bf16 MFMA: wfT[m,n] = sum_k Wfb[k,m]*Wfa[n,k]
    tcast<<<dim3(32, 2), blk, 0, stream>>>(Wfb, tfbT, 128, HID);
    cast_bf16<<<dim3(128), blk, 0, stream>>>(Wfa, wfa16, (int)((size_t)HID * 128 / 8));
    gemm_bf16<true><<<dim3(16, 16, 1), blk, 0, stream>>>(
        tfbT, tfbT, tfbT, tfbT, wfa16, wfa16, wfa16, wfa16,
        wfT, wfT, wfT, wfT, HID, HID, 128);

    // q,k,v,g projections in ONE launch
    gemm_bf16<false><<<dim3(32, 16, 4), blk, 0, stream>>>(
        hb16, hb16, hb16, hb16, wqT, wkT, wvT, wfT,
        qb, kb, vb, gb, M, HID, HID);

    // beta
    gemm_n16<<<dim3(M / 16), blk, 0, stream>>>(h, Wb, betab, M, HID);

    // conv + SiLU (segmented, race-free via halo snapshot)
    halo_save<<<dim3(432), blk, 0, stream>>>(qb, kb, vb, halb);
    conv_silu<<<dim3(192), blk, 0, stream>>>(qb, kb, vb, cwq, cwk, cwv, halb);

    // l2norm q/k, g -> exp(g)
    prep_qkg<<<dim3(16384), blk, 0, stream>>>(qb, kb, gb, A_log, dtb, M * 16);

    // gated delta-rule scan (R13-proven configuration)
    kda_scan<<<dim3(1024), dim3(64), 0, stream>>>(qb, kb, vb, gb, betab, ob);

    // gate path: compose Wg = Wga@Wgb (bf16 MFMA, reuse small scratch + wqT)
    tcast<<<dim3(32, 2), blk, 0, stream>>>(Wgb, tfbT, 128, HID);
    cast_bf16<<<dim3(128), blk, 0, stream>>>(Wga, wfa16, (int)((size_t)HID * 128 / 8));
    gemm_bf16<true><<<dim3(16, 16, 1), blk, 0, stream>>>(
        tfbT, tfbT, tfbT, tfbT, wfa16, wfa16, wfa16, wfa16,
        wqT, wqT, wqT, wqT, HID, HID, 128);
    gemm_bf16<false><<<dim3(32, 16, 1), blk, 0, stream>>>(
        hb16, hb16, hb16, hb16, wqT, wqT, wqT, wqT,
        gateb, gateb, gateb, gateb, M, HID, HID);

    // gated RMSNorm -> bf16 (fused cast)
    norm_gate<<<dim3(16384), blk, 0, stream>>>(ob, gateb, nw, obb16, M * 16);

    // output projection
    tcast<<<dim3(32, 32), blk, 0, stream>>>(Wo, wkT, HID, HID);
    gemm_bf16<false><<<dim3(32, 16, 1), blk, 0, stream>>>(
        obb16, obb16, obb16, obb16, wkT, wkT, wkT, wkT,
        out, out, out, out, M, HID, HID);
}

// Round 17
// 1014.096 us; speedup vs baseline: 1.2926x; 1.1828x over previous
//
#include <hip/hip_runtime.h>
#include <hip/hip_bf16.h>

// ---------------------------------------------------------------------------
// KimiDeltaAttention — round 17.
//  * scan: R13-proven kernel, minus the per-step sigmoid (beta now
//    pre-sigmoided in gemm_n16's epilogue).
//  * gate GEMM moved PRE-scan, writes bf16 into the dead wvT+wfT region
//    (exact [M,HID] ushort fit); norm_gate reads bf16 gate.
//  * tcast/compose launches batched via blockIdx.z (16 -> 13 dispatches).
// ---------------------------------------------------------------------------

using short8 = __attribute__((ext_vector_type(8))) short;
using f32x4  = __attribute__((ext_vector_type(4))) float;

static __device__ __forceinline__ ushort f2bf(float f) {
    __hip_bfloat16 h = __float2bfloat16(f);
    return *reinterpret_cast<ushort*>(&h);
}
static __device__ __forceinline__ float bf2f(ushort u) {
    return __int_as_float(((int)u) << 16);
}

// DPP butterfly/rotation adds (VALU-speed, no LDS pipe)
static __device__ __forceinline__ float qadd1(float x) {
    int y = __builtin_amdgcn_mov_dpp(__float_as_int(x), 0xB1, 0xF, 0xF, true);
    return x + __int_as_float(y);
}
static __device__ __forceinline__ float qadd2(float x) {
    int y = __builtin_amdgcn_mov_dpp(__float_as_int(x), 0x4E, 0xF, 0xF, true);
    return x + __int_as_float(y);
}
static __device__ __forceinline__ float radd4(float x) {
    int y = __builtin_amdgcn_mov_dpp(__float_as_int(x), 0x124, 0xF, 0xF, true);
    return x + __int_as_float(y);
}
static __device__ __forceinline__ float radd8(float x) {
    int y = __builtin_amdgcn_mov_dpp(__float_as_int(x), 0x128, 0xF, 0xF, true);
    return x + __int_as_float(y);
}
static __device__ __forceinline__ float rsum16(float x) {
    x = qadd1(x);
    x = qadd2(x);
    x = radd4(x);
    x = radd8(x);
    return x;
}

template<int W, int R> struct BufIdx { static constexpr int w = W, r = R; };

// ----------------------- row-major f32 -> bf16 cast -------------------------
__global__ __launch_bounds__(256) void cast_bf16(const float* __restrict__ in,
                                                 ushort* __restrict__ out, int n8)
{
    const int i = blockIdx.x * 256 + threadIdx.x;
    if (i >= n8) return;
    const float4 a = ((const float4*)in)[2 * i];
    const float4 b = ((const float4*)in)[2 * i + 1];
    ushort u[8] = {f2bf(a.x), f2bf(a.y), f2bf(a.z), f2bf(a.w),
                   f2bf(b.x), f2bf(b.y), f2bf(b.z), f2bf(b.w)};
    ((uint4*)out)[i] = *(uint4*)u;
}

// ------- transpose-cast: f32 [R,C] -> bf16 [C,R], z picks (in,out) ----------
__global__ __launch_bounds__(256) void tcast(
    const float* __restrict__ i0, const float* __restrict__ i1,
    const float* __restrict__ i2, ushort* __restrict__ o0,
    ushort* __restrict__ o1, ushort* __restrict__ o2, int R, int C)
{
    const int z = blockIdx.z;
    const float* in = (z == 0) ? i0 : (z == 1) ? i1 : i2;
    ushort* out     = (z == 0) ? o0 : (z == 1) ? o1 : o2;

    __shared__ float tile[64][68];
    const int t  = threadIdx.x;
    const int c0 = blockIdx.x * 64, r0 = blockIdx.y * 64;
    const int lr = t >> 2, lc = (t & 3) * 16;
#pragma unroll
    for (int j = 0; j < 4; ++j) {
        const float4 v = *(const float4*)&in[(size_t)(r0 + lr) * C + c0 + lc + 4 * j];
        *(float4*)&tile[lr][lc + 4 * j] = v;
    }
    __syncthreads();
    const int oc = t >> 2, och = (t & 3) * 16;
    uint u[8];
#pragma unroll
    for (int j = 0; j < 8; ++j) {
        const float f0 = tile[och + 2 * j][oc];
        const float f1 = tile[och + 2 * j + 1][oc];
        u[j] = (uint)f2bf(f0) | ((uint)f2bf(f1) << 16);
    }
    uint4* dst = (uint4*)&out[(size_t)(c0 + oc) * R + r0 + och];
    dst[0] = make_uint4(u[0], u[1], u[2], u[3]);
    dst[1] = make_uint4(u[4], u[5], u[6], u[7]);
}

// --------------- bf16 MFMA GEMM: C[M,N] = A[M,K] @ Bt[N,K]^T ----------------
// 128x128 tile, BK=64, 4 waves. Staging: global_load_lds width=16, linear
// LDS dest, pre-swizzled global source (chunk c = (lane&7)^(lane>>3)).
template<bool OUT16>
__global__ __launch_bounds__(256) void gemm_bf16(
    const ushort* __restrict__ A0, const ushort* __restrict__ A1,
    const ushort* __restrict__ A2, const ushort* __restrict__ A3,
    const ushort* __restrict__ B0, const ushort* __restrict__ B1,
    const ushort* __restrict__ B2, const ushort* __restrict__ B3,
    void* __restrict__ C0, void* __restrict__ C1,
    void* __restrict__ C2, void* __restrict__ C3,
    int M, int N, int K)
{
    const int z = blockIdx.z;
    const ushort* A = (z == 0) ? A0 : (z == 1) ? A1 : (z == 2) ? A2 : A3;
    const ushort* B = (z == 0) ? B0 : (z == 1) ? B1 : (z == 2) ? B2 : B3;
    void* Cv       = (z == 0) ? C0 : (z == 1) ? C1 : (z == 2) ? C2 : C3;

    __shared__ ushort As[128 * 64];
    __shared__ ushort Bs[128 * 64];

    const int tid  = threadIdx.x;
    const int lane = tid & 63;
    const int wave = tid >> 6;
    const int wm = wave >> 1, wn = wave & 1;
    const int bm = blockIdx.x * 128, bn = blockIdx.y * 128;

    const int ml = lane & 15;
    const int g  = lane >> 4;

    const int lrow = lane >> 3;                  // 0..7
    const int cofs = ((lane & 7) ^ lrow) * 8;    // swizzled 16B chunk offset

    f32x4 acc[4][4];
#pragma unroll
    for (int i = 0; i < 4; ++i)
#pragma unroll
        for (int j = 0; j < 4; ++j) acc[i][j] = (f32x4){0.f, 0.f, 0.f, 0.f};

    for (int k0 = 0; k0 < K; k0 += 64) {
#pragma unroll
        for (int i = 0; i < 4; ++i) {
            const int row = wave * 32 + i * 8 + lrow;
            const ushort* gA = A + (size_t)(bm + row) * K + k0 + cofs;
            const ushort* gB = B + (size_t)(bn + row) * K + k0 + cofs;
            ushort* lA = As + (wave * 32 + i * 8) * 64;
            ushort* lB = Bs + (wave * 32 + i * 8) * 64;
            __builtin_amdgcn_global_load_lds(
                (const __attribute__((address_space(1))) void*)gA,
                (__attribute__((address_space(3))) void*)lA, 16, 0, 0);
            __builtin_amdgcn_global_load_lds(
                (const __attribute__((address_space(1))) void*)gB,
                (__attribute__((address_space(3))) void*)lB, 16, 0, 0);
        }
        __syncthreads();
#pragma unroll
        for (int kk = 0; kk < 2; ++kk) {
            short8 af[4], bfr[4];
#pragma unroll
            for (int mi = 0; mi < 4; ++mi) {
                const int row = wm * 64 + mi * 16 + ml;
                const int sw  = ((row * 128 + (kk * 4 + g) * 16) ^ ((ml & 7) << 4)) >> 1;
                af[mi] = *(const short8*)&As[sw];
            }
#pragma unroll
            for (int ni = 0; ni < 4; ++ni) {
                const int row = wn * 64 + ni * 16 + ml;
                const int sw  = ((row * 128 + (kk * 4 + g) * 16) ^ ((ml & 7) << 4)) >> 1;
                bfr[ni] = *(const short8*)&Bs[sw];
            }
#pragma unroll
            for (int mi = 0; mi < 4; ++mi)
#pragma unroll
                for (int ni = 0; ni < 4; ++ni)
                    acc[mi][ni] = __builtin_amdgcn_mfma_f32_16x16x32_bf16(
                        af[mi], bfr[ni], acc[mi][ni], 0, 0, 0);
        }
        __syncthreads();
    }

#pragma unroll
    for (int mi = 0; mi < 4; ++mi)
#pragma unroll
        for (int ni = 0; ni < 4; ++ni) {
            const int col = bn + wn * 64 + ni * 16 + ml;
#pragma unroll
            for (int r = 0; r < 4; ++r) {
                const int row = bm + wm * 64 + mi * 16 + g * 4 + r;
                if constexpr (OUT16) {
                    ((ushort*)Cv)[(size_t)row * N + col] = f2bf(acc[mi][ni][r]);
                } else {
                    ((float*)Cv)[(size_t)row * N + col] = acc[mi][ni][r];
                }
            }
        }
}

// --------- small-N GEMM for beta: N = 16, sigmoid fused in epilogue --------
__global__ __launch_bounds__(256) void gemm_n16(
    const float* __restrict__ A, const float* __restrict__ B,
    float* __restrict__ C, int M, int Kd)
{
    const int tid  = threadIdx.x;
    const int n    = tid & 15;
    const int mloc = tid >> 4;
    const int m    = blockIdx.x * 16 + mloc;
    const float* a  = A + (size_t)m * Kd;
    const float* bn = B + n;
    float acc = 0.f;
#pragma unroll 4
    for (int k0 = 0; k0 < Kd; k0 += 8) {
        float4 a0 = *(const float4*)(a + k0);
        float4 a1 = *(const float4*)(a + k0 + 4);
        acc = fmaf(a0.x, bn[(size_t)(k0 + 0) * 16], acc);
        acc = fmaf(a0.y, bn[(size_t)(k0 + 1) * 16], acc);
        acc = fmaf(a0.z, bn[(size_t)(k0 + 2) * 16], acc);
        acc = fmaf(a0.w, bn[(size_t)(k0 + 3) * 16], acc);
        acc = fmaf(a1.x, bn[(size_t)(k0 + 4) * 16], acc);
        acc = fmaf(a1.y, bn[(size_t)(k0 + 5) * 16], acc);
        acc = fmaf(a1.z, bn[(size_t)(k0 + 6) * 16], acc);
        acc = fmaf(a1.w, bn[(size_t)(k0 + 7) * 16], acc);
    }
    C[(size_t)m * 16 + n] = 1.f / (1.f + __expf(-acc));   // pre-sigmoided beta
}

// ---- halo save: pre-conv values at segment boundaries (race-free split) ----
__global__ __launch_bounds__(256) void halo_save(
    const float* __restrict__ q, const float* __restrict__ k,
    const float* __restrict__ v, float* __restrict__ hal)
{
    constexpr int T = 2048, C = 2048, SEG = 512;
    const int idx = blockIdx.x * 256 + threadIdx.x;   // < 9*12288
    const int cid = idx % 12288;
    const int sh  = idx / 12288;      // 0..8
    const int sg  = sh / 3 + 1;       // segment 1..3
    const int ho  = sh % 3;           // halo offset 0..2
    const int which = cid >> 12, rem = cid & 4095, b = rem >> 11, c = rem & 2047;
    const float* x = (which == 0) ? q : (which == 1) ? k : v;
    hal[idx] = x[(size_t)b * T * C + (size_t)(sg * SEG - 3 + ho) * C + c];
}

// ------- depthwise causal conv (K=4) + SiLU, in-place, 4 T-segments ---------
__global__ __launch_bounds__(256) void conv_silu(
    float* __restrict__ q, float* __restrict__ k, float* __restrict__ v,
    const float* __restrict__ wq, const float* __restrict__ wk,
    const float* __restrict__ wv, const float* __restrict__ hal)
{
    constexpr int T = 2048, C = 2048, SEG = 512;
    const int seg    = blockIdx.x & 3;
    const int colblk = blockIdx.x >> 2;
    const int cid    = colblk * 256 + threadIdx.x;
    const int which  = cid >> 12;
    const int rem    = cid & 4095;
    const int b      = rem >> 11;
    const int c      = rem & 2047;
    float* x        = (which == 0) ? q : (which == 1) ? k : v;
    const float* w  = (which == 0) ? wq : (which == 1) ? wk : wv;

    const float w0 = w[c * 4 + 0], w1 = w[c * 4 + 1];
    const float w2 = w[c * 4 + 2], w3 = w[c * 4 + 3];
    float* p = x + (size_t)b * T * C + c;
    float xm3, xm2, xm1;
    if (seg == 0) { xm3 = xm2 = xm1 = 0.f; }
    else {
        xm3 = hal[((seg - 1) * 3 + 0) * 12288 + cid];
        xm2 = hal[((seg - 1) * 3 + 1) * 12288 + cid];
        xm1 = hal[((seg - 1) * 3 + 2) * 12288 + cid];
    }

    const int t0s = seg * SEG;
    for (int t0 = t0s; t0 < t0s + SEG; t0 += 16) {
        float xt[16], yo[16];
#pragma unroll
        for (int j = 0; j < 16; ++j) xt[j] = p[(size_t)(t0 + j) * C];
#pragma unroll
        for (int j = 0; j < 16; ++j) {
            float y = fmaf(xm3, w0, fmaf(xm2, w1, fmaf(xm1, w2, xt[j] * w3)));
            yo[j] = y / (1.f + __expf(-y));
            xm3 = xm2; xm2 = xm1; xm1 = xt[j];
        }
#pragma unroll
        for (int j = 0; j < 16; ++j) p[(size_t)(t0 + j) * C] = yo[j];
    }
}

// ------ prep: l2norm(q)*D^-0.5, l2norm(k), g -> exp(-exp(A_log)*softplus) ---
__global__ __launch_bounds__(256) void prep_qkg(
    float* __restrict__ Qb, float* __restrict__ Kb, float* __restrict__ Gb,
    const float* __restrict__ A_log, const float* __restrict__ dt_bias,
    int rows)
{
    const int wave = threadIdx.x >> 6;
    const int lane = threadIdx.x & 63;
    const int row  = blockIdx.x * 4 + wave;
    if (row >= rows) return;
    const int hh = row & 15;
    const size_t base = (size_t)row * 128;

    float q0 = Qb[base + lane], q1 = Qb[base + 64 + lane];
    float k0 = Kb[base + lane], k1 = Kb[base + 64 + lane];
    float sq = q0 * q0 + q1 * q1;
    float sk = k0 * k0 + k1 * k1;
#pragma unroll
    for (int off = 32; off >= 1; off >>= 1) {
        sq += __shfl_xor(sq, off);
        sk += __shfl_xor(sk, off);
    }
    const float qs = rsqrtf(sq + 1e-6f) * 0.08838834764831845f;
    const float ks = rsqrtf(sk + 1e-6f);
    Qb[base + lane] = q0 * qs; Qb[base + 64 + lane] = q1 * qs;
    Kb[base + lane] = k0 * ks; Kb[base + 64 + lane] = k1 * ks;

    const float a = __expf(A_log[hh]);
    float x0 = Gb[base + lane]      + dt_bias[hh * 128 + lane];
    float x1 = Gb[base + 64 + lane] + dt_bias[hh * 128 + 64 + lane];
    float sp0 = (x0 > 20.f) ? x0 : log1pf(__expf(x0));
    float sp1 = (x1 > 20.f) ? x1 : log1pf(__expf(x1));
    Gb[base + lane]      = __expf(-a * sp0);
    Gb[base + 64 + lane] = __expf(-a * sp1);
}

// --------------------- gated delta-rule sequential scan ---------------------
// R13-proven; beta arrives pre-sigmoided (no transcendental in the loop).
__global__ __launch_bounds__(64, 1) void kda_scan(
    const float* __restrict__ Q, const float* __restrict__ Kk,
    const float* __restrict__ V, const float* __restrict__ EG,
    const float* __restrict__ Bsig, float* __restrict__ O)
{
    constexpr int T = 2048, H = 16, HD = 2048;
    const int bid = blockIdx.x;
    const int bh  = bid & 31;
    const int vg  = bid >> 5;          // 0..31
    const int b = bh >> 4, hh = bh & 15;
    const int lane = threadIdx.x;
    const int col  = lane >> 4;        // 0..3
    const int sl   = lane & 15;        // 0..15
    const int vcol = vg * 4 + col;

    __shared__ __align__(16) float k_s[3][128];
    __shared__ __align__(16) float e_s[3][128];
    __shared__ __align__(16) float q_s[3][128];

    float s[8];
#pragma unroll
    for (int i = 0; i < 8; ++i) s[i] = 0.f;

    const size_t tok0 = (size_t)b * T;
    const int cb = hh * 128;
    const float* qp = Q  + tok0 * HD + cb;
    const float* kp = Kk + tok0 * HD + cb;
    const float* ep = EG + tok0 * HD + cb;
    const float* vp = V  + tok0 * HD + cb;
    const float* bp = Bsig + tok0 * H + hh;
    float* op = O + tok0 * HD + cb;

    const int d0 = 2 * lane;
    const int cw = lane >> 1;
    const int pw = cw ^ (cw >> 3);
    const int stpos = pw * 4 + (d0 & 3);

    const int c0r = 2 * sl, c1r = 2 * sl + 1;
    const int rof0 = (c0r ^ (c0r >> 3)) << 2;
    const int rof1 = (c1r ^ (c1r >> 3)) << 2;

    {
        *(float2*)&k_s[0][stpos] = *(const float2*)&kp[d0];
        *(float2*)&e_s[0][stpos] = *(const float2*)&ep[d0];
        *(float2*)&q_s[0][stpos] = *(const float2*)&qp[d0];
        *(float2*)&k_s[1][stpos] = *(const float2*)&kp[HD + d0];
        *(float2*)&e_s[1][stpos] = *(const float2*)&ep[HD + d0];
        *(float2*)&q_s[1][stpos] = *(const float2*)&qp[HD + d0];
    }
    float2 FaK = *(const float2*)&kp[(size_t)2 * HD + d0];
    float2 FaE = *(const float2*)&ep[(size_t)2 * HD + d0];
    float2 FaQ = *(const float2*)&qp[(size_t)2 * HD + d0];
    float2 FbK = *(const float2*)&kp[(size_t)3 * HD + d0];
    float2 FbE = *(const float2*)&ep[(size_t)3 * HD + d0];
    float2 FbQ = *(const float2*)&qp[(size_t)3 * HD + d0];
    float v0 = vp[vcol];
    float v1 = vp[(size_t)1 * HD + vcol];
    float v2 = vp[(size_t)2 * HD + vcol];
    float v3 = vp[(size_t)3 * HD + vcol];
    float beta = bp[0];                    // pre-sigmoided
    float br1 = bp[(size_t)1 * H];
    float br2 = bp[(size_t)2 * H];
    float br3 = bp[(size_t)3 * H];

    __syncthreads();

    float4 KX[2], EX[2], QX[2], KY[2], EY[2], QY[2];
    KX[0] = *(const float4*)&k_s[0][rof0];
    KX[1] = *(const float4*)&k_s[0][rof1];
    EX[0] = *(const float4*)&e_s[0][rof0];
    EX[1] = *(const float4*)&e_s[0][rof1];
    QX[0] = *(const float4*)&q_s[0][rof0];
    QX[1] = *(const float4*)&q_s[0][rof1];

    auto step = [&](auto bi, const int t,
                    float4* KF, float4* EF, float4* QF,
                    float4* KG, float4* EGr, float4* QG,
                    float2& Fk, float2& Fe, float2& Fq) {
        constexpr int W = decltype(bi)::w;
        constexpr int R = decltype(bi)::r;
        KG[0]  = *(const float4*)&k_s[R][rof0];
        KG[1]  = *(const float4*)&k_s[R][rof1];
        EGr[0] = *(const float4*)&e_s[R][rof0];
        EGr[1] = *(const float4*)&e_s[R][rof1];
        QG[0]  = *(const float4*)&q_s[R][rof0];
        QG[1]  = *(const float4*)&q_s[R][rof1];
        *(float2*)&k_s[W][stpos] = Fk;
        *(float2*)&e_s[W][stpos] = Fe;
        *(float2*)&q_s[W][stpos] = Fq;
        {
            const size_t o4 = (size_t)(t + 4) * HD;
            Fk = *(const float2*)&kp[o4 + d0];
            Fe = *(const float2*)&ep[o4 + d0];
            Fq = *(const float2*)&qp[o4 + d0];
        }
        float a0, a1, a2, a3;
        {
            float s0 = s[0] * EF[0].x, s1 = s[1] * EF[0].y;
            float s2 = s[2] * EF[0].z, s3 = s[3] * EF[0].w;
            float s4 = s[4] * EF[1].x, s5 = s[5] * EF[1].y;
            float s6 = s[6] * EF[1].z, s7 = s[7] * EF[1].w;
            s[0] = s0; s[1] = s1; s[2] = s2; s[3] = s3;
            s[4] = s4; s[5] = s5; s[6] = s6; s[7] = s7;
            a0 = KF[0].x * s0; a1 = KF[0].y * s1;
            a2 = KF[0].z * s2; a3 = KF[0].w * s3;
            a0 = fmaf(KF[1].x, s4, a0); a1 = fmaf(KF[1].y, s5, a1);
            a2 = fmaf(KF[1].z, s6, a2); a3 = fmaf(KF[1].w, s7, a3);
        }
        float kS = rsum16((a0 + a1) + (a2 + a3));
        const float delta = beta * (v0 - kS);
        float o0, o1, o2v, o3v;
        {
            float s0 = fmaf(KF[0].x, delta, s[0]);
            float s1 = fmaf(KF[0].y, delta, s[1]);
            float s2 = fmaf(KF[0].z, delta, s[2]);
            float s3 = fmaf(KF[0].w, delta, s[3]);
            float s4 = fmaf(KF[1].x, delta, s[4]);
            float s5 = fmaf(KF[1].y, delta, s[5]);
            float s6 = fmaf(KF[1].z, delta, s[6]);
            float s7 = fmaf(KF[1].w, delta, s[7]);
            s[0] = s0; s[1] = s1; s[2] = s2; s[3] = s3;
            s[4] = s4; s[5] = s5; s[6] = s6; s[7] = s7;
            o0 = QF[0].x * s0; o1 = QF[0].y * s1;
            o2v = QF[0].z * s2; o3v = QF[0].w * s3;
            o0 = fmaf(QF[1].x, s4, o0); o1 = fmaf(QF[1].y, s5, o1);
            o2v = fmaf(QF[1].z, s6, o2v); o3v = fmaf(QF[1].w, s7, o3v);
        }
        float oo = rsum16((o0 + o1) + (o2v + o3v));
        if (sl == 0) op[(size_t)t * HD + vcol] = oo;
        {
            const float vn = vp[(size_t)(t + 4) * HD + vcol];
            const float bn = bp[(size_t)(t + 4) * H];
            v0 = v1; v1 = v2; v2 = v3; v3 = vn;
            beta = br1; br1 = br2; br2 = br3; br3 = bn;
        }
    };

    for (int t = 0; t < T - 2; t += 6) {
        step(BufIdx<2, 1>{}, t + 0, KX, EX, QX, KY, EY, QY, FaK, FaE, FaQ);
        step(BufIdx<0, 2>{}, t + 1, KY, EY, QY, KX, EX, QX, FbK, FbE, FbQ);
        step(BufIdx<1, 0>{}, t + 2, KX, EX, QX, KY, EY, QY, FaK, FaE, FaQ);
        step(BufIdx<2, 1>{}, t + 3, KY, EY, QY, KX, EX, QX, FbK, FbE, FbQ);
        step(BufIdx<0, 2>{}, t + 4, KX, EX, QX, KY, EY, QY, FaK, FaE, FaQ);
        step(BufIdx<1, 0>{}, t + 5, KY, EY, QY, KX, EX, QX, FbK, FbE, FbQ);
    }
    step(BufIdx<2, 1>{}, T - 2, KX, EX, QX, KY, EY, QY, FaK, FaE, FaQ);
    step(BufIdx<0, 2>{}, T - 1, KY, EY, QY, KX, EX, QX, FbK, FbE, FbQ);
}

// ---- gated RMSNorm: obf16 = rms(o)*norm_w*sigmoid(gate_bf16), bf16 out -----
__global__ __launch_bounds__(256) void norm_gate(
    const float* __restrict__ O, const ushort* __restrict__ Gate16,
    const float* __restrict__ norm_w, ushort* __restrict__ Out16, int rows)
{
    const int wave = threadIdx.x >> 6;
    const int lane = threadIdx.x & 63;
    const int row  = blockIdx.x * 4 + wave;
    if (row >= rows) return;
    const size_t base = (size_t)row * 128;

    float o0 = O[base + lane], o1 = O[base + 64 + lane];
    float ss = o0 * o0 + o1 * o1;
#pragma unroll
    for (int off = 32; off >= 1; off >>= 1) ss += __shfl_xor(ss, off);
    const float scale = rsqrtf(ss * (1.f / 128.f) + 1e-6f);

    const float g0 = bf2f(Gate16[base + lane]);
    const float g1 = bf2f(Gate16[base + 64 + lane]);
    o0 = o0 * scale * norm_w[lane]      * (1.f / (1.f + __expf(-g0)));
    o1 = o1 * scale * norm_w[64 + lane] * (1.f / (1.f + __expf(-g1)));
    Out16[base + lane]      = f2bf(o0);
    Out16[base + 64 + lane] = f2bf(o1);
}

// ---------------------------------------------------------------------------
extern "C" void kernel_launch(void* const* d_in, const int* in_sizes, int n_in,
                              void* d_out, int out_size, void* d_ws, size_t ws_size,
                              hipStream_t stream)
{
    const float* h    = (const float*)d_in[0];
    const float* Wq   = (const float*)d_in[1];
    const float* Wk   = (const float*)d_in[2];
    const float* Wv   = (const float*)d_in[3];
    const float* cwq  = (const float*)d_in[4];
    const float* cwk  = (const float*)d_in[5];
    const float* cwv  = (const float*)d_in[6];
    const float* A_log= (const float*)d_in[7];
    const float* dtb  = (const float*)d_in[8];
    const float* Wfa  = (const float*)d_in[9];
    const float* Wfb  = (const float*)d_in[10];
    const float* Wb   = (const float*)d_in[11];
    const float* Wga  = (const float*)d_in[12];
    const float* Wgb  = (const float*)d_in[13];
    const float* nw   = (const float*)d_in[14];
    const float* Wo   = (const float*)d_in[15];
    float* out = (float*)d_out;

    const int M = 4096, HID = 2048;
    const size_t big = (size_t)M * HID;        // 8M elements
    float* ws    = (float*)d_ws;
    float* qb    = ws;
    float* kb    = qb + big;
    float* vb    = kb + big;    // post-norm: obb16 (ushort)
    float* gb    = vb + big;
    float* ob    = gb + big;
    float* betab = ob + big;                        // 4096x16 (sigmoided)
    float* halb  = betab + (size_t)M * 16;          // 110592
    ushort* hb16 = (ushort*)(halb + 110592);        // [M,HID] bf16
    ushort* wqT  = hb16 + big;                      // [2048,2048] bf16 (x5)
    ushort* wkT  = wqT + (size_t)HID * HID;
    ushort* wvT  = wkT + (size_t)HID * HID;
    ushort* wfT  = wvT + (size_t)HID * HID;
    ushort* wgT  = wfT + (size_t)HID * HID;
    ushort* tfbT = wgT + (size_t)HID * HID;         // [2048,128] bf16 x2
    ushort* tgbT = tfbT + (size_t)HID * 128;
    ushort* wfa16= tgbT + (size_t)HID * 128;        // [2048,128] bf16 x2
    ushort* wga16= wfa16 + (size_t)HID * 128;

    ushort* gate16 = wvT;            // gate bf16 output: spans wvT+wfT (dead)
    ushort* obb16  = (ushort*)vb;

    dim3 blk(256);

    // casts / transposes (batched)
    cast_bf16<<<dim3(4096), blk, 0, stream>>>(h, hb16, (int)(big / 8));
    tcast<<<dim3(32, 32, 3), blk, 0, stream>>>(Wq, Wk, Wv, wqT, wkT, wvT, HID, HID);
    tcast<<<dim3(32, 2, 2), blk, 0, stream>>>(Wfb, Wgb, Wgb, tfbT, tgbT, tgbT, 128, HID);
    cast_bf16<<<dim3(128), blk, 0, stream>>>(Wfa, wfa16, (int)((size_t)HID * 128 / 8));
    cast_bf16<<<dim3(128), blk, 0, stream>>>(Wga, wga16, (int)((size_t)HID * 128 / 8));

    // compose Wf = Wfa@Wfb, Wg = Wga@Wgb (bf16 MFMA, one z=2 launch)
    gemm_bf16<true><<<dim3(16, 16, 2), blk, 0, stream>>>(
        tfbT, tgbT, tgbT, tgbT, wfa16, wga16, wga16, wga16,
        wfT, wgT, wgT, wgT, HID, HID, 128);

    // q,k,v,g projections in ONE z=4 launch
    gemm_bf16<false><<<dim3(32, 16, 4), blk, 0, stream>>>(
        hb16, hb16, hb16, hb16, wqT, wkT, wvT, wfT,
        qb, kb, vb, gb, M, HID, HID);

    // gate projection (pre-scan, bf16 out into dead wvT+wfT region)
    gemm_bf16<true><<<dim3(32, 16, 1), blk, 0, stream>>>(
        hb16, hb16, hb16, hb16, wgT, wgT, wgT, wgT,
        gate16, gate16, gate16, gate16, M, HID, HID);

    // beta (sigmoid fused)
    gemm_n16<<<dim3(M / 16), blk, 0, stream>>>(h, Wb, betab, M, HID);

    // conv + SiLU (segmented, race-free via halo snapshot)
    halo_save<<<dim3(432), blk, 0, stream>>>(qb, kb, vb, halb);
    conv_silu<<<dim3(192), blk, 0, stream>>>(qb, kb, vb, cwq, cwk, cwv, halb);

    // l2norm q/k, g -> exp(g)
    prep_qkg<<<dim3(16384), blk, 0, stream>>>(qb, kb, gb, A_log, dtb, M * 16);

    // gated delta-rule scan (R13-proven configuration)
    kda_scan<<<dim3(1024), dim3(64), 0, stream>>>(qb, kb, vb, gb, betab, ob);

    // gated RMSNorm -> bf16 (reads bf16 gate)
    norm_gate<<<dim3(16384), blk, 0, stream>>>(ob, gate16, nw, obb16, M * 16);

    // output projection (Wo transposed into dead wqT)
    tcast<<<dim3(32, 32, 1), blk, 0, stream>>>(Wo, Wo, Wo, wqT, wqT, wqT, HID, HID);
    gemm_bf16<false><<<dim3(32, 16, 1), blk, 0, stream>>>(
        obb16, obb16, obb16, obb16, wqT, wqT, wqT, wqT,
        out, out, out, out, M, HID, HID);
}